// Round 5
// baseline (102.844 us; speedup 1.0000x reference)
//
#include <hip/hip_runtime.h>

#define N_NODES 20000
#define N_EDGES 40000
#define NB 32
#define NS 32
#define NT 64
#define NCH 40                  // hist/scatter chunks of 1024 edges
#define EPC 1024
#define NPREP 64                // prep blocks: 0..39 hist, 40..59 node bounds, all zero out
#define KBN 8                   // blocks per node segment in main
#define KBE 8                   // blocks per edge segment in main
#define TILE 256                // items staged per block round
#define STEP200 12.9032258065f  // 200*step, step = 2/31
#define WB 0.992f               // band half-width in s units => |z| <= 12.8

// ws layout (ints): chist[NCH*NB] | node_base[33] | ebase[33] | pad | sedge[E] (int2)

// ---------- node 1: zero out + edge histogram + node segment bounds ----------
__global__ __launch_bounds__(256) void prep_kernel(
        const int* __restrict__ ei, const int* __restrict__ batch,
        int* __restrict__ chist, int* __restrict__ node_base,
        float* __restrict__ out_zero) {
    const int t = threadIdx.x;
    const int bid = blockIdx.x;
    for (int idx = bid * 256 + t; idx < NB * NS * NT; idx += NPREP * 256)
        out_zero[idx] = 0.0f;

    if (bid < NCH) {                       // edge histogram, 1024 edges/block
        __shared__ int h[NB];
        if (t < NB) h[t] = 0;
        __syncthreads();
#pragma unroll
        for (int k = 0; k < 4; k++) {
            const int e = bid * EPC + k * 256 + t;
            if (e < N_EDGES) atomicAdd(&h[batch[ei[e]]], 1);   // LDS atomic
        }
        __syncthreads();
        if (t < NB) chist[bid * NB + t] = h[t];
    } else if (bid < 60) {                 // node segment bounds (batch sorted)
#pragma unroll
        for (int k = 0; k < 4; k++) {
            const int n = (bid - NCH) * 1024 + k * 256 + t;
            if (n < N_NODES) {
                const int bn = batch[n];
                const int bp = (n == 0) ? -1 : batch[n - 1];
                for (int b = bp + 1; b <= bn; b++) node_base[b] = n;
                if (n == N_NODES - 1)
                    for (int b = bn + 1; b <= NB; b++) node_base[b] = N_NODES;
            }
        }
    }
}

// ---------- node 2: scatter with inline (redundant per-block) scan ----------
__global__ __launch_bounds__(256) void scatter_kernel(
        const int* __restrict__ ei, const int* __restrict__ batch,
        const int* __restrict__ chist, int* __restrict__ ebase_g,
        int2* __restrict__ sedge) {
    __shared__ int cursor[NB];
    __shared__ int base[NB];
    const int t = threadIdx.x;
    if (t < NB) {
        int tot = 0, pre = 0;
#pragma unroll
        for (int c = 0; c < NCH; c++) {
            const int vv = chist[c * NB + t];
            tot += vv;
            if (c < (int)blockIdx.x) pre += vv;
        }
        base[t] = tot;
        cursor[t] = pre;
    }
    __syncthreads();
    if (t == 0) {
        int run = 0;
        for (int b = 0; b < NB; b++) { const int vv = base[b]; base[b] = run; run += vv; }
        if (blockIdx.x == 0) ebase_g[NB] = run;
    }
    __syncthreads();
    if (t < NB) {
        cursor[t] += base[t];
        if (blockIdx.x == 0) ebase_g[t] = base[t];
    }
    __syncthreads();
#pragma unroll
    for (int k = 0; k < 4; k++) {
        const int e = blockIdx.x * EPC + k * 256 + t;
        if (e < N_EDGES) {
            const int s = ei[e];
            const int d = ei[N_EDGES + e];
            const int b = batch[s];
            const int p = atomicAdd(&cursor[b], 1);   // LDS atomic
            sedge[p] = make_int2(s, d);
        }
    }
}

// ---------- node 3: main accumulation (band trick + LDS-staged items) --------
// Grid: 32 node segments x KBN + 32 edge segments x KBE = 512 blocks (2/CU).
// Each block owns a CONTIGUOUS sub-range of one segment. Per 256-item tile:
// parallel coalesced/gathered staging of item coords into LDS, then waves
// consume items round-robin via LDS broadcast reads (kills the serial
// scalar-load latency chain of R4). lane = theta; <=2 thresholds in the
// sigmoid transition band; saturated-ones tail via diff[] prefix at flush.
__global__ __launch_bounds__(256) void ect_main_kernel(
        const float* __restrict__ x, const float* __restrict__ v,
        const int* __restrict__ node_base, const int* __restrict__ ebase,
        const int2* __restrict__ sedge,
        float* __restrict__ out) {
    __shared__ float acc[NS * NT];        // 8 KB
    __shared__ int   diff[(NS + 1) * NT]; // 8.45 KB, slot NS = dump
    __shared__ float xs[TILE * 6];        // staged coords (3/node, 6/edge)
    const int t = threadIdx.x;
#pragma unroll
    for (int j = 0; j < 8; j++) acc[t + 256 * j] = 0.0f;
    for (int idx = t; idx < (NS + 1) * NT; idx += 256) diff[idx] = 0;

    const int lane = t & 63;
    const int wid  = t >> 6;
    const bool is_node = blockIdx.x < NB * KBN;
    int b, lo, hi; float w;
    if (is_node) {
        b = blockIdx.x / KBN;
        const int slice = blockIdx.x % KBN;
        const int s0 = node_base[b], s1 = node_base[b + 1];
        const int len = (s1 - s0 + KBN - 1) / KBN;
        lo = s0 + slice * len; hi = min(s1, lo + len); w = 1.0f;
    } else {
        const int q = blockIdx.x - NB * KBN;
        b = q / KBE;
        const int slice = q % KBE;
        const int s0 = ebase[b], s1 = ebase[b + 1];
        const int len = (s1 - s0 + KBE - 1) / KBE;
        lo = s0 + slice * len; hi = min(s1, lo + len); w = -0.5f;
    }
    const float v0 = v[lane], v1 = v[NT + lane], v2 = v[2 * NT + lane];
    __syncthreads();   // acc/diff zero-init visible

    for (int base = lo; base < hi; base += TILE) {   // bounds block-uniform
        const int cnt = min(TILE, hi - base);
        if (t < cnt) {                               // stage tile
            if (is_node) {
                const int n = base + t;
                xs[3 * t]     = x[3 * n];
                xs[3 * t + 1] = x[3 * n + 1];
                xs[3 * t + 2] = x[3 * n + 2];
            } else {
                const int2 e2 = sedge[base + t];
                xs[6 * t]     = x[3 * e2.x];
                xs[6 * t + 1] = x[3 * e2.x + 1];
                xs[6 * t + 2] = x[3 * e2.x + 2];
                xs[6 * t + 3] = x[3 * e2.y];
                xs[6 * t + 4] = x[3 * e2.y + 1];
                xs[6 * t + 5] = x[3 * e2.y + 2];
            }
        }
        __syncthreads();
        for (int j = wid; j < cnt; j += 4) {         // wave-round-robin items
            float h;
            if (is_node) {
                h = fmaf(xs[3 * j], v0, fmaf(xs[3 * j + 1], v1, xs[3 * j + 2] * v2));
            } else {
                const float hs = fmaf(xs[6 * j],     v0, fmaf(xs[6 * j + 1], v1, xs[6 * j + 2] * v2));
                const float hd = fmaf(xs[6 * j + 3], v0, fmaf(xs[6 * j + 4], v1, xs[6 * j + 5] * v2));
                h = fmaxf(hs, hd);
            }
            const float t200h = 200.0f * h;
            const float u = (h + 1.0f) * 15.5f;      // fractional grid index
            const int kb = (int)ceilf(u - WB);
            const int ke = (int)floorf(u + WB) + 1;
#pragma unroll
            for (int jj = 0; jj < 2; jj++) {         // band spans <= 2 ints
                const int s = kb + jj;
                if (s < ke && s >= 0 && s < NS) {
                    const float z = fmaf((float)s, STEP200, -200.0f) - t200h;
                    const float sig = __builtin_amdgcn_rcpf(1.0f + __expf(-z));
                    atomicAdd(&acc[s * NT + lane], sig);   // ds_add_f32
                }
            }
            const int kec = min(max(ke, 0), NS);
            atomicAdd(&diff[kec * NT + lane], 1);          // ds_add_u32
        }
        __syncthreads();
    }

    // integrate ones-counts: acc[s][lane] += sum_{k<=s} diff[k][lane]
    if (t < NT) {
        int run = 0;
#pragma unroll
        for (int s = 0; s < NS; s++) {
            run += diff[s * NT + t];
            acc[s * NT + t] += (float)run;
        }
    }
    __syncthreads();

    float* ob = out + b * (NS * NT);
#pragma unroll
    for (int j = 0; j < 8; j++) {
        const int idx = t + 256 * j;
        const float val = acc[idx];
        if (val != 0.0f) atomicAdd(&ob[idx], w * val);
    }
}

// ---------- launcher ----------
extern "C" void kernel_launch(void* const* d_in, const int* in_sizes, int n_in,
                              void* d_out, int out_size, void* d_ws, size_t ws_size,
                              hipStream_t stream) {
    const float* x   = (const float*)d_in[0];   // [N,3]
    const float* v   = (const float*)d_in[1];   // [3,64]
    // d_in[2] = lin: linspace(-1,1,32) hardcoded analytically
    const int*   ei  = (const int*)d_in[3];     // [2,E]
    const int*   bat = (const int*)d_in[4];     // [N], sorted

    float* out = (float*)d_out;                 // [32,32,64]

    int* chist     = (int*)d_ws;
    int* node_base = chist + NCH * NB;          // 33 ints
    int* ebase     = node_base + 33;            // 33 ints
    int2* sedge    = (int2*)(chist + NCH * NB + 68);  // even int offset -> 8B aligned

    prep_kernel<<<NPREP, 256, 0, stream>>>(ei, bat, chist, node_base, out);
    scatter_kernel<<<NCH, 256, 0, stream>>>(ei, bat, chist, ebase, sedge);
    ect_main_kernel<<<NB * KBN + NB * KBE, 256, 0, stream>>>(
        x, v, node_base, ebase, sedge, out);
}